// Round 3
// baseline (248.244 us; speedup 1.0000x reference)
//
#include <hip/hip_runtime.h>
#include <stdint.h>

#define NUM_CLASSES 80u
#define TOPK 1000
#define CONF_T 0.05f
#define NMS_T 0.6f
#define MAX_COORD 4096.0f
#define TARGET 1152u            // top-1000 + tie/superset slack
#define NB 1024u                // kA grid size (== kF1 thread count)
#define SLOTS 96u               // candidate slots per block (mean 27.6, max~54)
#define LINCAP (NB * SLOTS)     // flat candidate array size (98304)
#define SRVCAP 2048u            // survivor buffer (>= TARGET + boundary ties)
#define STATIC_F 4.0f           // static candidate prefilter threshold
#define STATIC_KEY 0xC0800000u  // fkey(+4.0f)
#define LCAP 256u               // per-block LDS candidate staging (kA)

typedef unsigned long long ull;
typedef ull ull2 __attribute__((ext_vector_type(2)));
typedef uint32_t uint4v __attribute__((ext_vector_type(4)));

// Monotone float->uint key: descending float == descending key
__device__ __forceinline__ uint32_t fkey(float x) {
  uint32_t k = __float_as_uint(x);
  return (k & 0x80000000u) ? ~k : (k | 0x80000000u);
}

// Inclusive suffix sum of per-thread v across 1024 threads (3 barriers).
// part = LDS[16]. Returns sum_{t' >= t} v[t']; part[0] ends as grand total.
__device__ __forceinline__ uint32_t suffix_scan_1024(uint32_t v, uint32_t* part,
                                                     int t) {
  int lane = t & 63, wid = t >> 6;
#pragma unroll
  for (int off = 1; off < 64; off <<= 1) {
    uint32_t x = __shfl_down(v, off);
    if (lane + off < 64) v += x;
  }
  if (lane == 0) part[wid] = v;  // lane 0 holds wave total
  __syncthreads();
  if (wid == 0) {
    uint32_t pv = (lane < 16) ? part[lane] : 0u;
#pragma unroll
    for (int off = 1; off < 16; off <<= 1) {
      uint32_t x = __shfl_down(pv, off);
      if (lane + off < 16) pv += x;
    }
    if (lane < 16) part[lane] = pv;  // inclusive suffix of wave totals
  }
  __syncthreads();
  uint32_t after = (wid < 15) ? part[wid + 1] : 0u;
  return v + after;
}

// ---------------- kernel A: stream + static compact (slotted, NO atomics) -
// Per-block fixed slot regions + plain cnt[b] store: no global counter, no
// zeroing dispatch. Unused KEY slots are padded with 0 so kF1 can read the
// whole region coalesced; any key < STATIC_KEY (pad or stale poison) is
// filtered by every consumer pass. Overflow (cnt[b] > SLOTS) routes kF1 to
// the full-rescan fallback.
__global__ void __launch_bounds__(256) kA(const float4* __restrict__ cls, int n4,
                                          uint32_t* __restrict__ cnt,
                                          uint32_t* __restrict__ candKey,
                                          uint32_t* __restrict__ candIdx) {
  __shared__ uint32_t lk[LCAP];       // local candidate keys
  __shared__ uint32_t li[LCAP];       // local candidate idxs
  __shared__ uint32_t lcnt;
  if (threadIdx.x == 0) lcnt = 0u;
  __syncthreads();
  int stride = gridDim.x * blockDim.x;
  for (int i = blockIdx.x * blockDim.x + threadIdx.x; i < n4; i += stride) {
    float4 v = cls[i];
    float f4[4] = {v.x, v.y, v.z, v.w};
#pragma unroll
    for (int c = 0; c < 4; ++c) {
      if (f4[c] >= STATIC_F) {
        uint32_t p = atomicAdd(&lcnt, 1u);  // LDS atomic: cheap, distributed
        if (p < LCAP) { lk[p] = fkey(f4[c]); li[p] = (uint32_t)i * 4u + c; }
      }
    }
  }
  __syncthreads();
  uint32_t c = lcnt;
  if (threadIdx.x == 0) cnt[blockIdx.x] = c;  // raw count; >SLOTS => overflow
  uint32_t m = c; if (m > SLOTS) m = SLOTS;
  uint32_t base = blockIdx.x * SLOTS;
  for (uint32_t i = threadIdx.x; i < SLOTS; i += 256u)
    candKey[base + i] = (i < m) ? lk[i] : 0u;   // pad keys -> filterable
  for (uint32_t i = threadIdx.x; i < m; i += 256u)
    candIdx[base + i] = li[i];
}

// ---------------- kernel F1: pick threshold + select survivors ------------
// Single block, 1024 threads. Round-8 lessons (r2: kF1 = 67us, VALUBusy
// 0.03%): (a) per-thread serial slot walks = uncoalesced latency chains ->
// read the padded slot array FLAT with uint4 strided loops; (b) coarse bin
// k>>20 put ~52% of candidates in ONE bin (~15K serialized same-address LDS
// atomics) -> bin (k-STATIC_KEY)>>13 spreads range [4.0,...) across 4096
// bins (hottest ~0.6%); (c) survivor-count atomic wave-aggregated.
// FALLBACK (overflow / total < TARGET / bin clamp; never on bench data):
// full 4096-bin k>>20 histogram over all 21M logits, compact, refine.
__global__ void __launch_bounds__(1024) kF1(
    const float4* __restrict__ cls4, int n4, const float* __restrict__ cls,
    const uint32_t* __restrict__ cnt, uint32_t* __restrict__ candKey,
    uint32_t* __restrict__ candIdx, uint32_t* __restrict__ sel,
    ull* __restrict__ srv, float* __restrict__ out, float* __restrict__ topScore) {
  __shared__ uint32_t fh[4096];
  __shared__ uint32_t part[16];
  __shared__ uint32_t lidx[SRVCAP];
  __shared__ uint32_t scnt, bselS, AS, TkeyS, ovS, linNS;
  int tid = threadIdx.x;
  int lane = tid & 63;

  uint32_t myc = cnt[tid];                       // raw per-block count
  if (tid == 0) { ovS = 0u; scnt = 0u; }
  for (int i = tid; i < 4096; i += 1024) fh[i] = 0u;
  __syncthreads();
  if (myc > SLOTS) atomicOr(&ovS, 1u);
  uint32_t cc = (myc > SLOTS) ? SLOTS : myc;
  (void)suffix_scan_1024(cc, part, tid);         // part[0] = grand total
  uint32_t n_total = part[0];
  bool fast = (ovS == 0u) && (n_total >= TARGET);  // block-uniform

  if (fast) {
    // ---- coarse select: coalesced flat read, bin = (k-STATIC_KEY)>>13 ----
    const uint4v* ck4 = (const uint4v*)candKey;
    for (uint32_t i = tid; i < LINCAP / 4u; i += 1024u) {
      uint4v k4 = ck4[i];
#pragma unroll
      for (int c = 0; c < 4; ++c) {
        uint32_t k = k4[c];
        if (k >= STATIC_KEY) {
          uint32_t b = (k - STATIC_KEY) >> 13;
          if (b > 4095u) b = 4095u;              // x >= ~64: impossible guard
          atomicAdd(&fh[b], 1u);
        }
      }
    }
    __syncthreads();
    uint32_t c0 = fh[tid * 4 + 0], c1 = fh[tid * 4 + 1];
    uint32_t c2 = fh[tid * 4 + 2], c3 = fh[tid * 4 + 3];
    uint32_t v = c0 + c1 + c2 + c3;
    uint32_t suff = suffix_scan_1024(v, part, tid);
    uint32_t above = suff - v;
    if (suff >= TARGET && above < TARGET) {      // unique crossing thread
      uint32_t cum = above;
      uint32_t ccv[4] = {c0, c1, c2, c3};
      for (int j = 3; j >= 0; --j) {
        if (cum + ccv[j] >= TARGET) { bselS = (uint32_t)(tid * 4 + j); AS = cum; break; }
        cum += ccv[j];
      }
    }
    __syncthreads();
    if (bselS == 4095u) fast = false;            // clamped bin: demote
  }
  if (!fast) {
    // ---- FALLBACK: full k>>20 histogram + compact from this block ----
    for (int i = tid; i < 4096; i += 1024) fh[i] = 0u;
    __syncthreads();
    for (int i = tid; i < n4; i += 1024) {
      float4 v = cls4[i];
      atomicAdd(&fh[fkey(v.x) >> 20], 1u);
      atomicAdd(&fh[fkey(v.y) >> 20], 1u);
      atomicAdd(&fh[fkey(v.z) >> 20], 1u);
      atomicAdd(&fh[fkey(v.w) >> 20], 1u);
    }
    __syncthreads();
    uint32_t c0 = fh[tid * 4 + 0], c1 = fh[tid * 4 + 1];
    uint32_t c2 = fh[tid * 4 + 2], c3 = fh[tid * 4 + 3];
    uint32_t v = c0 + c1 + c2 + c3;
    uint32_t suff = suffix_scan_1024(v, part, tid);
    uint32_t above = suff - v;
    if (suff >= TARGET && above < TARGET) {      // total 21M >= TARGET always
      uint32_t cum = above;
      uint32_t ccv[4] = {c0, c1, c2, c3};
      for (int j = 3; j >= 0; --j) {
        if (cum + ccv[j] >= TARGET) { bselS = (uint32_t)(tid * 4 + j); AS = cum; break; }
        cum += ccv[j];
      }
    }
    if (tid == 0) linNS = 0u;
    __syncthreads();
    uint32_t bs = bselS;
    for (int i = tid; i < n4; i += 1024) {
      float4 v4 = cls4[i];
      uint32_t k4[4] = {fkey(v4.x), fkey(v4.y), fkey(v4.z), fkey(v4.w)};
#pragma unroll
      for (int c = 0; c < 4; ++c) {
        if ((k4[c] >> 20) >= bs) {
          uint32_t p = atomicAdd(&linNS, 1u);
          if (p < LINCAP) { candKey[p] = k4[c]; candIdx[p] = (uint32_t)i * 4u + c; }
        }
      }
    }
    __syncthreads();
  }
  __syncthreads();
  uint32_t bsel = bselS, A = AS;
  uint32_t ln = fast ? (uint32_t)LINCAP : (linNS > LINCAP ? LINCAP : linNS);

  // ---- common fine stage: 10-bit refine within bin bsel ----
  if (tid < 1024) fh[tid] = 0u;
  __syncthreads();
  for (uint32_t i = tid; i < ln; i += 1024u) {
    uint32_t k = candKey[i];
    bool in; uint32_t fb;
    if (fast) { in = (k >= STATIC_KEY) && (((k - STATIC_KEY) >> 13) == bsel);
                fb = (k >> 3) & 1023u; }
    else      { in = ((k >> 20) == bsel);
                fb = (k >> 10) & 1023u; }
    if (in) atomicAdd(&fh[fb], 1u);
  }
  __syncthreads();
  uint32_t v2 = fh[tid];
  uint32_t suff2 = suffix_scan_1024(v2, part, tid);
  uint32_t above2 = suff2 - v2;
  if ((A + suff2 >= TARGET) && (A + above2 < TARGET))
    TkeyS = fast ? (STATIC_KEY + (bsel << 13) + ((uint32_t)tid << 3))
                 : ((bsel << 20) | ((uint32_t)tid << 10));
  if (tid == 0 && A + suff2 < TARGET)            // degenerate: take all in bin
    TkeyS = fast ? (STATIC_KEY + (bsel << 13)) : (bsel << 20);
  __syncthreads();
  uint32_t T = TkeyS;

  // ---- selection: wave-aggregated counter (1 LDS atomic per wave-iter) ----
  for (uint32_t i = tid; i < ln; i += 1024u) {
    uint32_t k = candKey[i];
    bool p = (k >= T);
    ull m = __ballot(p);
    uint32_t nb = (uint32_t)__popcll(m);
    if (nb) {
      int fa = __ffsll((long long)__ballot(true)) - 1;  // first active lane
      uint32_t wb = 0u;
      if (lane == fa) wb = atomicAdd(&scnt, nb);
      wb = __shfl(wb, fa);
      if (p) {
        uint32_t pos = wb + (uint32_t)__popcll(m & ((1ull << lane) - 1ull));
        if (pos < SRVCAP) lidx[pos] = candIdx[i];
      }
    }
  }
  __syncthreads();
  uint32_t c = scnt; if (c > SRVCAP) c = SRVCAP;
  if (tid == 0) sel[4] = c;                      // plain store, one block
  for (uint32_t i = tid; i < c; i += 1024u) {
    uint32_t idx = lidx[i];
    float x = cls[idx];
    float p = 1.0f / (1.0f + expf(-x));          // np fp32 sigmoid
    srv[i] = ((ull)__float_as_uint(p) << 32) | (ull)(uint32_t)(~idx);
  }
  // prefill (covers degenerate scount < 1000; cheap)
  for (int i = tid; i < 4000; i += 1024) out[i] = 0.0f;
  for (int i = tid; i < 1000; i += 1024) { out[5000 + i] = 0.0f; topScore[i] = 0.0f; }
}

// ---------------- kernel F2: rank survivors + emit ------------------------
// 32 blocks x 64: stage all survivor keys into LDS; thread i computes
// rank_i = #{j: skey_j > skey_i} (exact, ull keys unique via ~idx low bits)
// and emits row rank_i. Kept separate from kF1: LDS broadcast throughput is
// per-CU, so spreading the 1152^2 compare matrix across 32 CUs wins.
__global__ void __launch_bounds__(64) kF2(
    const float* __restrict__ box, const int* __restrict__ ph,
    const int* __restrict__ pw, const uint32_t* __restrict__ sel,
    const ull* __restrict__ srv, float* __restrict__ out,
    float* __restrict__ topScore, float* __restrict__ obox) {
  __shared__ __align__(16) ull sk[SRVCAP];
  int t = threadIdx.x;
  uint32_t scount = sel[4]; if (scount > SRVCAP) scount = SRVCAP;
  uint32_t pad = (scount + 1u) & ~1u;
  for (uint32_t i = t; i < pad; i += 64u) sk[i] = (i < scount) ? srv[i] : 0ull;
  __syncthreads();
  uint32_t i = blockIdx.x * 64u + (uint32_t)t;
  if (i >= scount) return;
  ull my = sk[i];
  uint32_t rank = 0;
#pragma unroll 4
  for (uint32_t j = 0; j < pad; j += 2u) {
    ull2 v = *reinterpret_cast<const ull2*>(&sk[j]);  // b128 broadcast read
    rank += (v.x > my) + (v.y > my);
  }
  if (rank >= TOPK) return;
  uint32_t idx = ~(uint32_t)my;
  float p = __uint_as_float((uint32_t)(my >> 32));
  uint32_t label = idx % NUM_CLASSES;
  uint32_t anchor = idx / NUM_CLASSES;
  float W = (float)pw[0], H = (float)ph[0];
  float b0 = box[anchor * 4u + 0u], b1 = box[anchor * 4u + 1u];
  float b2 = box[anchor * 4u + 2u], b3 = box[anchor * 4u + 3u];
  out[rank * 4 + 0] = fminf(fmaxf(b0 / W, 0.0f), 1.0f);
  out[rank * 4 + 1] = fminf(fmaxf(b1 / H, 0.0f), 1.0f);
  out[rank * 4 + 2] = fminf(fmaxf(b2 / W, 0.0f), 1.0f);
  out[rank * 4 + 3] = fminf(fmaxf(b3 / H, 0.0f), 1.0f);
  out[5000 + rank] = (float)label;
  topScore[rank] = p;
  float off = (float)label * MAX_COORD;  // class-aware NMS offset
  obox[rank * 4 + 0] = b0 + off; obox[rank * 4 + 1] = b1 + off;
  obox[rank * 4 + 2] = b2 + off; obox[rank * 4 + 3] = b3 + off;
}

// ---------------- kernel G: IoU suppression bitmasks (j > i) --------------
__global__ void kG(const float* __restrict__ obox, ull* __restrict__ masks) {
  int i = blockIdx.x;  // row 0..999
  float x1i = obox[i * 4 + 0], y1i = obox[i * 4 + 1];
  float x2i = obox[i * 4 + 2], y2i = obox[i * 4 + 3];
  float ai = (x2i - x1i) * (y2i - y1i);
  for (int base = 0; base < 1024; base += 256) {
    int jj = base + (int)threadIdx.x;
    bool bit = false;
    if (jj < TOPK && jj > i) {
      float x1j = obox[jj * 4 + 0], y1j = obox[jj * 4 + 1];
      float x2j = obox[jj * 4 + 2], y2j = obox[jj * 4 + 3];
      float aj = (x2j - x1j) * (y2j - y1j);
      float ix1 = fmaxf(x1i, x1j), iy1 = fmaxf(y1i, y1j);
      float ix2 = fminf(x2i, x2j), iy2 = fminf(y2i, y2j);
      float iw = fmaxf(ix2 - ix1, 0.0f), ih = fmaxf(iy2 - iy1, 0.0f);
      float inter = iw * ih;
      float iou = inter / (ai + aj - inter + 1e-9f);
      bit = iou > NMS_T;
    }
    ull m = __ballot(bit);
    if ((threadIdx.x & 63u) == 0u) masks[i * 16 + (jj >> 6)] = m;
  }
}

// ---------------- kernel H: LDS-staged single-wave greedy NMS -------------
__global__ void __launch_bounds__(256) kH(const float* __restrict__ topScore,
                                          const ull* __restrict__ masks,
                                          float* __restrict__ out) {
  __shared__ ull lmask[TOPK * 16];
  __shared__ uint32_t nzrow[TOPK];
  __shared__ ull keepsh[16];
  int t = threadIdx.x;
  for (int i = t; i < TOPK; i += 256) nzrow[i] = 0u;
  if (t < 16) keepsh[t] = 0ull;
  __syncthreads();
  for (int i = t; i < TOPK * 16; i += 256) {
    ull m = masks[i];
    lmask[i] = m;
    if (m) atomicOr(&nzrow[i >> 4], 1u);
  }
  for (int base = 0; base < 1024; base += 256) {
    int r = base + t;
    bool v = (r < TOPK) && (topScore[r] > CONF_T);
    ull b = __ballot(v);
    if ((t & 63) == 0) keepsh[(base >> 6) + (t >> 6)] = b;
  }
  __syncthreads();
  if (t < 64) {  // single-wave greedy loop, no barriers inside
    ull kw = (t < 16) ? keepsh[t] : 0ull;
    ull nzw = 0ull;
    if (t < 16) {
      for (int b = 0; b < 64; ++b) {
        int r = t * 64 + b;
        if (r < TOPK && nzrow[r]) nzw |= 1ull << b;
      }
    }
    for (int w = 0; w < 16; ++w) {
      ull cur = __shfl(kw, w) & __shfl(nzw, w);
      while (cur) {
        int b = __ffsll((long long)cur) - 1;
        int i = w * 64 + b;
        if (t < 16) kw &= ~lmask[i * 16 + t];  // row i suppresses only j > i
        ull nk = __shfl(kw, w);
        cur = nk & __shfl(nzw, w);
        cur &= (b == 63) ? 0ull : (~0ull << (b + 1));
      }
    }
    if (t < 16) keepsh[t] = kw;
  }
  __syncthreads();
  for (int r = t; r < TOPK; r += 256) {
    bool k = (keepsh[r >> 6] >> (r & 63)) & 1ull;
    float s = topScore[r];
    out[4000 + r] = k ? s : 0.0f;
    out[6000 + r] = k ? 1.0f : 0.0f;
  }
}

extern "C" void kernel_launch(void* const* d_in, const int* in_sizes, int n_in,
                              void* d_out, int out_size, void* d_ws, size_t ws_size,
                              hipStream_t stream) {
  const float* cls = (const float*)d_in[0];  // (1, N, 80) logits
  const float* box = (const float*)d_in[1];  // (1, N, 4)
  const int* ph = (const int*)d_in[2];       // img_h
  const int* pw = (const int*)d_in[3];       // img_w
  float* out = (float*)d_out;                // [boxes 4000 | scores 1000 | labels 1000 | keep 1000]
  int n = in_sizes[0];                       // 20,971,520 (divisible by 4)

  uint8_t* w = (uint8_t*)d_ws;
  uint32_t* cnt     = (uint32_t*)(w);                               // 4 KB
  uint32_t* sel     = (uint32_t*)(w + 4096);                        // 64 B (pad 4 KB)
  uint32_t* candKey = (uint32_t*)(w + 8192);                        // 384 KB
  uint32_t* candIdx = (uint32_t*)(w + 8192 + (size_t)LINCAP * 4);   // 384 KB
  ull*      srv     = (ull*)     (w + 8192 + (size_t)LINCAP * 8);   // 16 KB
  float*    topScore= (float*)   (w + 8192 + (size_t)LINCAP * 8 + 16384);          // 4 KB
  float*    obox    = (float*)   (w + 8192 + (size_t)LINCAP * 8 + 16384 + 4096);   // 16 KB
  ull*      masks   = (ull*)     (w + 8192 + (size_t)LINCAP * 8 + 16384 + 4096 + 16384); // 128 KB

  kA <<<NB, 256, 0, stream>>>((const float4*)cls, n / 4, cnt, candKey, candIdx);
  kF1<<<1, 1024, 0, stream>>>((const float4*)cls, n / 4, cls, cnt, candKey, candIdx, sel, srv, out, topScore);
  kF2<<<SRVCAP / 64, 64, 0, stream>>>(box, ph, pw, sel, srv, out, topScore, obox);
  kG <<<TOPK, 256, 0, stream>>>(obox, masks);
  kH <<<1, 256, 0, stream>>>(topScore, masks, out);
}

// Round 4
// 210.192 us; speedup vs baseline: 1.1810x; 1.1810x over previous
//
#include <hip/hip_runtime.h>
#include <stdint.h>

#define NUM_CLASSES 80u
#define TOPK 1000
#define CONF_T 0.05f
#define NMS_T 0.6f
#define MAX_COORD 4096.0f
#define TARGET 1152u            // top-1000 + tie/superset slack
#define CAP 49152u              // linear candidate buffer capacity
#define SRVCAP 2048u            // survivor buffer (>= TARGET + boundary ties)
#define STATIC_F 4.0f           // static candidate prefilter threshold
#define STATIC_KEY 0xC0800000u  // fkey(+4.0f)
#define NBINS 4096              // spread bins: (k - STATIC_KEY) >> 13
#define BINSH 13
#define LCAP 512u               // per-block LDS candidate staging (kA)
#define PBLK 1024u              // per-block survivor staging (kSel)

typedef unsigned long long ull;
typedef ull ull2 __attribute__((ext_vector_type(2)));

// Monotone float->uint key: descending float == descending key
__device__ __forceinline__ uint32_t fkey(float x) {
  uint32_t k = __float_as_uint(x);
  return (k & 0x80000000u) ? ~k : (k | 0x80000000u);
}

// Inclusive suffix sum of per-thread v across 256 threads (2 barriers).
__device__ __forceinline__ uint32_t suffix_scan_256(uint32_t v, uint32_t* part,
                                                    int t) {
  int lane = t & 63, wid = t >> 6;  // 4 waves
#pragma unroll
  for (int off = 1; off < 64; off <<= 1) {
    uint32_t x = __shfl_down(v, off);
    if (lane + off < 64) v += x;
  }
  if (lane == 0) part[wid] = v;  // wave totals
  __syncthreads();
  if (wid == 0 && lane < 4) {
    uint32_t pv = part[lane];
#pragma unroll
    for (int off = 1; off < 4; off <<= 1) {
      uint32_t x = __shfl_down(pv, off);
      if (lane + off < 4) pv += x;
    }
    part[lane] = pv;  // inclusive suffix of wave totals
  }
  __syncthreads();
  uint32_t after = (wid < 3) ? part[wid + 1] : 0u;
  return v + after;
}

// Suffix-scan hl[NBINSX] with 256 threads (contiguous chunk per thread) and
// find the crossing bin for `target`: unique thread writes bin/A/cnt.
// A = count strictly above bin; cnt = hl[bin]; A < target <= A + cnt.
template <int NBINSX>
__device__ __forceinline__ void pick_bin(const uint32_t* hl, uint32_t target,
                                         int t, uint32_t* part, uint32_t* binS,
                                         uint32_t* AS, uint32_t* cntS) {
  const int CH = NBINSX / 256;
  uint32_t s = 0;
#pragma unroll
  for (int j = 0; j < CH; ++j) s += hl[t * CH + j];
  uint32_t incl = suffix_scan_256(s, part, t);
  uint32_t after = incl - s;  // suffix strictly after my chunk
  if (incl >= target && after < target) {  // crossing inside my chunk: unique
    uint32_t cum = after;
    for (int j = CH - 1; j >= 0; --j) {
      uint32_t h = hl[t * CH + j];
      if (cum + h >= target) { *binS = (uint32_t)(t * CH + j); *AS = cum; *cntS = h; break; }
      cum += h;
    }
  }
}

// ---------------- kernel Z: zero hist+sel, prefill outputs ----------------
__global__ void __launch_bounds__(256) kz(uint32_t* hist, uint32_t* sel,
                                          float* out, float* topScore) {
  int g = blockIdx.x * 256 + threadIdx.x;  // 16 x 256 = 4096
  hist[g] = 0u;
  if (g < 16) sel[g] = 0u;
  for (int i = g; i < 4000; i += 4096) out[i] = 0.0f;  // boxes prefill
  if (g < 1000) { out[5000 + g] = 0.0f; topScore[g] = 0.0f; }  // labels/scores
}

// ---------------- kernel A: stream + compact + spread-bin histogram -------
// r1-proven shape: LDS-staged candidates, ONE global atomicAdd per block.
// Added: per-candidate atomicAdd into a GLOBAL 4096-bin histogram with
// spread binning (k-STATIC_KEY)>>13 (~28K atomics over 16 KB: negligible).
// The hist is complete even if candKey overflows CAP, so the threshold
// derived from it is always exact.
__global__ void __launch_bounds__(256) kA(const float4* __restrict__ cls, int n4,
                                          uint32_t* __restrict__ sel,
                                          uint32_t* __restrict__ hist,
                                          uint32_t* __restrict__ candKey,
                                          uint32_t* __restrict__ candIdx) {
  __shared__ uint32_t lk[LCAP];
  __shared__ uint32_t li[LCAP];
  __shared__ uint32_t lcnt, gbase;
  if (threadIdx.x == 0) lcnt = 0u;
  __syncthreads();
  int stride = gridDim.x * blockDim.x;
  for (int i = blockIdx.x * blockDim.x + threadIdx.x; i < n4; i += stride) {
    float4 v = cls[i];
    float f4[4] = {v.x, v.y, v.z, v.w};
#pragma unroll
    for (int c = 0; c < 4; ++c) {
      if (f4[c] >= STATIC_F) {
        uint32_t k = fkey(f4[c]);
        uint32_t b = (k - STATIC_KEY) >> BINSH; if (b > NBINS - 1u) b = NBINS - 1u;
        atomicAdd(&hist[b], 1u);
        uint32_t p = atomicAdd(&lcnt, 1u);  // LDS atomic: cheap, distributed
        if (p < LCAP) { lk[p] = k; li[p] = (uint32_t)i * 4u + c; }
        else {  // spill (correctness-only; ~never taken)
          uint32_t gp = atomicAdd(&sel[2], 1u);
          if (gp < CAP) { candKey[gp] = k; candIdx[gp] = (uint32_t)i * 4u + c; }
        }
      }
    }
  }
  __syncthreads();
  uint32_t c = lcnt; if (c > LCAP) c = LCAP;
  if (threadIdx.x == 0 && c) gbase = atomicAdd(&sel[2], c);  // ONE per block
  __syncthreads();
  for (uint32_t i = threadIdx.x; i < c; i += 256u) {
    uint32_t gp = gbase + i;
    if (gp < CAP) { candKey[gp] = lk[i]; candIdx[gp] = li[i]; }
  }
}

// ---------------- kernel Sel: multi-block threshold + survivor select -----
// Round-9 lesson (r2: 67us, r3: 78us @ VALUBusy 0.08%): a single-block
// consumer of 1024-block-producer data is cross-XCD-latency-bound no matter
// how coalesced. Fix: 64 blocks each REDUNDANTLY stage the 16 KB histogram,
// suffix-scan for the crossing bin, set T = bin floor (bin width ~4e-3 in x;
// TARGET slack absorbs the whole bin, no fine refine), then select their
// slice of candidates in parallel (LDS staging + one global atomic/block).
// Survivor order is arbitrary; kF2's ranking is order-independent.
// FALLBACK (n < TARGET or n > CAP; never on bench data): block 0 does the
// full single-block histogram + fine refine + select.
__global__ void __launch_bounds__(256) kSel(
    const float4* __restrict__ cls4, int n4,
    uint32_t* __restrict__ sel, const uint32_t* __restrict__ hist,
    const uint32_t* __restrict__ candKey, const uint32_t* __restrict__ candIdx,
    ull* __restrict__ srv) {
  __shared__ uint32_t hl[NBINS];       // 16 KB
  __shared__ uint32_t part[16];
  __shared__ uint32_t sk_[PBLK];       // staged survivor keys
  __shared__ uint32_t si_[PBLK];       // staged survivor idxs
  __shared__ uint32_t lcnt, gbase, binS, AS, cntS;
  int t = threadIdx.x;
  uint32_t n = sel[2];
  bool fb = (n < TARGET) || (n > CAP);

  if (!fb) {
    for (int i = t; i < NBINS; i += 256) hl[i] = hist[i];
    if (t == 0) { lcnt = 0u; binS = 0u; AS = 0u; cntS = 0u; }
    __syncthreads();
    pick_bin<NBINS>(hl, TARGET, t, part, &binS, &AS, &cntS);
    __syncthreads();
    uint32_t T;
    if (AS + cntS > SRVCAP)            // bin spike (adversarial ties only):
      T = STATIC_KEY + ((binS + 1u) << BINSH);  // take strictly-above set (=AS)
    else
      T = STATIC_KEY + (binS << BINSH);
    uint32_t stride = gridDim.x * blockDim.x;
    for (uint32_t i = blockIdx.x * 256u + (uint32_t)t; i < n; i += stride) {
      uint32_t k = candKey[i];
      if (k >= T) {
        uint32_t p = atomicAdd(&lcnt, 1u);
        if (p < PBLK) { sk_[p] = k; si_[p] = candIdx[i]; }
      }
    }
    __syncthreads();
    uint32_t c = lcnt; if (c > PBLK) c = PBLK;
    if (t == 0 && c) gbase = atomicAdd(&sel[4], c);  // ONE per block
    __syncthreads();
    for (uint32_t i = t; i < c; i += 256u) {
      uint32_t k = sk_[i];
      float x = __uint_as_float(k & 0x7fffffffu);  // all candidates positive
      float p = 1.0f / (1.0f + expf(-x));          // fp32 sigmoid
      uint32_t pos = gbase + i;
      if (pos < SRVCAP)
        srv[pos] = ((ull)__float_as_uint(p) << 32) | (ull)(uint32_t)(~si_[i]);
    }
  } else {
    if (blockIdx.x != 0) return;
    // ---- single-block full fallback ----
    for (int i = t; i < NBINS; i += 256) hl[i] = 0u;
    if (t == 0) { binS = 0u; AS = 0u; cntS = 0u; }
    __syncthreads();
    for (int i = t; i < n4; i += 256) {
      float4 v = cls4[i];
      atomicAdd(&hl[fkey(v.x) >> 20], 1u);
      atomicAdd(&hl[fkey(v.y) >> 20], 1u);
      atomicAdd(&hl[fkey(v.z) >> 20], 1u);
      atomicAdd(&hl[fkey(v.w) >> 20], 1u);
    }
    __syncthreads();
    pick_bin<NBINS>(hl, TARGET, t, part, &binS, &AS, &cntS);  // coarse k>>20
    __syncthreads();
    uint32_t b20 = binS, A = AS;
    for (int i = t; i < 1024; i += 256) hl[i] = 0u;
    if (t == 0) { binS = 0u; }
    __syncthreads();
    for (int i = t; i < n4; i += 256) {  // fine 10-bit hist within b20
      float4 v = cls4[i];
      uint32_t k4[4] = {fkey(v.x), fkey(v.y), fkey(v.z), fkey(v.w)};
#pragma unroll
      for (int c2 = 0; c2 < 4; ++c2)
        if ((k4[c2] >> 20) == b20) atomicAdd(&hl[(k4[c2] >> 10) & 1023u], 1u);
    }
    __syncthreads();
    uint32_t rem = TARGET - A;  // >= 1; fine total = hl-sum >= rem
    pick_bin<1024>(hl, rem, t, part, &binS, &AS, &cntS);
    __syncthreads();
    uint32_t T = (b20 << 20) | (binS << 10);
    for (int i = t; i < n4; i += 256) {
      float4 v = cls4[i];
      uint32_t k4[4] = {fkey(v.x), fkey(v.y), fkey(v.z), fkey(v.w)};
#pragma unroll
      for (int c2 = 0; c2 < 4; ++c2) {
        uint32_t k = k4[c2];
        if (k >= T) {
          uint32_t pos = atomicAdd(&sel[4], 1u);  // perf-irrelevant path
          if (pos < SRVCAP) {
            float x = (k & 0x80000000u) ? __uint_as_float(k & 0x7fffffffu)
                                        : __uint_as_float(~k);
            float p = 1.0f / (1.0f + expf(-x));
            uint32_t idx = (uint32_t)i * 4u + c2;
            srv[pos] = ((ull)__float_as_uint(p) << 32) | (ull)(uint32_t)(~idx);
          }
        }
      }
    }
  }
}

// ---------------- kernel F2: rank survivors + emit ------------------------
// 32 blocks x 64: stage all survivor keys into LDS; thread i computes
// rank_i = #{j: skey_j > skey_i} (exact, ull keys unique via ~idx low bits)
// and emits row rank_i. Order-independent, so kSel's arbitrary survivor
// order is fine. Ties: larger ~idx == smaller idx wins, matching top_k.
__global__ void __launch_bounds__(64) kF2(
    const float* __restrict__ box, const int* __restrict__ ph,
    const int* __restrict__ pw, const uint32_t* __restrict__ sel,
    const ull* __restrict__ srv, float* __restrict__ out,
    float* __restrict__ topScore, float* __restrict__ obox) {
  __shared__ __align__(16) ull sk[SRVCAP];
  int t = threadIdx.x;
  uint32_t scount = sel[4]; if (scount > SRVCAP) scount = SRVCAP;
  uint32_t pad = (scount + 1u) & ~1u;
  for (uint32_t i = t; i < pad; i += 64u) sk[i] = (i < scount) ? srv[i] : 0ull;
  __syncthreads();
  uint32_t i = blockIdx.x * 64u + (uint32_t)t;
  if (i >= scount) return;
  ull my = sk[i];
  uint32_t rank = 0;
#pragma unroll 4
  for (uint32_t j = 0; j < pad; j += 2u) {
    ull2 v = *reinterpret_cast<const ull2*>(&sk[j]);  // b128 broadcast read
    rank += (v.x > my) + (v.y > my);
  }
  if (rank >= TOPK) return;
  uint32_t idx = ~(uint32_t)my;
  float p = __uint_as_float((uint32_t)(my >> 32));
  uint32_t label = idx % NUM_CLASSES;
  uint32_t anchor = idx / NUM_CLASSES;
  float W = (float)pw[0], H = (float)ph[0];
  float b0 = box[anchor * 4u + 0u], b1 = box[anchor * 4u + 1u];
  float b2 = box[anchor * 4u + 2u], b3 = box[anchor * 4u + 3u];
  out[rank * 4 + 0] = fminf(fmaxf(b0 / W, 0.0f), 1.0f);
  out[rank * 4 + 1] = fminf(fmaxf(b1 / H, 0.0f), 1.0f);
  out[rank * 4 + 2] = fminf(fmaxf(b2 / W, 0.0f), 1.0f);
  out[rank * 4 + 3] = fminf(fmaxf(b3 / H, 0.0f), 1.0f);
  out[5000 + rank] = (float)label;
  topScore[rank] = p;
  float off = (float)label * MAX_COORD;  // class-aware NMS offset
  obox[rank * 4 + 0] = b0 + off; obox[rank * 4 + 1] = b1 + off;
  obox[rank * 4 + 2] = b2 + off; obox[rank * 4 + 3] = b3 + off;
}

// ---------------- kernel G: IoU suppression bitmasks (j > i) --------------
__global__ void kG(const float* __restrict__ obox, ull* __restrict__ masks) {
  int i = blockIdx.x;  // row 0..999
  float x1i = obox[i * 4 + 0], y1i = obox[i * 4 + 1];
  float x2i = obox[i * 4 + 2], y2i = obox[i * 4 + 3];
  float ai = (x2i - x1i) * (y2i - y1i);
  for (int base = 0; base < 1024; base += 256) {
    int jj = base + (int)threadIdx.x;
    bool bit = false;
    if (jj < TOPK && jj > i) {
      float x1j = obox[jj * 4 + 0], y1j = obox[jj * 4 + 1];
      float x2j = obox[jj * 4 + 2], y2j = obox[jj * 4 + 3];
      float aj = (x2j - x1j) * (y2j - y1j);
      float ix1 = fmaxf(x1i, x1j), iy1 = fmaxf(y1i, y1j);
      float ix2 = fminf(x2i, x2j), iy2 = fminf(y2i, y2j);
      float iw = fmaxf(ix2 - ix1, 0.0f), ih = fmaxf(iy2 - iy1, 0.0f);
      float inter = iw * ih;
      float iou = inter / (ai + aj - inter + 1e-9f);
      bit = iou > NMS_T;
    }
    ull m = __ballot(bit);
    if ((threadIdx.x & 63u) == 0u) masks[i * 16 + (jj >> 6)] = m;
  }
}

// ---------------- kernel H: LDS-staged single-wave greedy NMS -------------
__global__ void __launch_bounds__(256) kH(const float* __restrict__ topScore,
                                          const ull* __restrict__ masks,
                                          float* __restrict__ out) {
  __shared__ ull lmask[TOPK * 16];
  __shared__ uint32_t nzrow[TOPK];
  __shared__ ull keepsh[16];
  int t = threadIdx.x;
  for (int i = t; i < TOPK; i += 256) nzrow[i] = 0u;
  if (t < 16) keepsh[t] = 0ull;
  __syncthreads();
  for (int i = t; i < TOPK * 16; i += 256) {
    ull m = masks[i];
    lmask[i] = m;
    if (m) atomicOr(&nzrow[i >> 4], 1u);
  }
  for (int base = 0; base < 1024; base += 256) {
    int r = base + t;
    bool v = (r < TOPK) && (topScore[r] > CONF_T);
    ull b = __ballot(v);
    if ((t & 63) == 0) keepsh[(base >> 6) + (t >> 6)] = b;
  }
  __syncthreads();
  if (t < 64) {  // single-wave greedy loop, no barriers inside
    ull kw = (t < 16) ? keepsh[t] : 0ull;
    ull nzw = 0ull;
    if (t < 16) {
      for (int b = 0; b < 64; ++b) {
        int r = t * 64 + b;
        if (r < TOPK && nzrow[r]) nzw |= 1ull << b;
      }
    }
    for (int w = 0; w < 16; ++w) {
      ull cur = __shfl(kw, w) & __shfl(nzw, w);
      while (cur) {
        int b = __ffsll((long long)cur) - 1;
        int i = w * 64 + b;
        if (t < 16) kw &= ~lmask[i * 16 + t];  // row i suppresses only j > i
        ull nk = __shfl(kw, w);
        cur = nk & __shfl(nzw, w);
        cur &= (b == 63) ? 0ull : (~0ull << (b + 1));
      }
    }
    if (t < 16) keepsh[t] = kw;
  }
  __syncthreads();
  for (int r = t; r < TOPK; r += 256) {
    bool k = (keepsh[r >> 6] >> (r & 63)) & 1ull;
    float s = topScore[r];
    out[4000 + r] = k ? s : 0.0f;
    out[6000 + r] = k ? 1.0f : 0.0f;
  }
}

extern "C" void kernel_launch(void* const* d_in, const int* in_sizes, int n_in,
                              void* d_out, int out_size, void* d_ws, size_t ws_size,
                              hipStream_t stream) {
  const float* cls = (const float*)d_in[0];  // (1, N, 80) logits
  const float* box = (const float*)d_in[1];  // (1, N, 4)
  const int* ph = (const int*)d_in[2];       // img_h
  const int* pw = (const int*)d_in[3];       // img_w
  float* out = (float*)d_out;                // [boxes 4000 | scores 1000 | labels 1000 | keep 1000]
  int n = in_sizes[0];                       // 20,971,520 (divisible by 4)

  uint8_t* w = (uint8_t*)d_ws;
  uint32_t* hist    = (uint32_t*)(w);                               // 16 KB
  uint32_t* sel     = (uint32_t*)(w + 16384);                       // 64 B (pad 4 KB)
  uint32_t* candKey = (uint32_t*)(w + 20480);                       // 192 KB
  uint32_t* candIdx = (uint32_t*)(w + 20480 + (size_t)CAP * 4);     // 192 KB
  ull*      srv     = (ull*)     (w + 20480 + (size_t)CAP * 8);     // 16 KB
  float*    topScore= (float*)   (w + 20480 + (size_t)CAP * 8 + 16384);          // 4 KB
  float*    obox    = (float*)   (w + 20480 + (size_t)CAP * 8 + 16384 + 4096);   // 16 KB
  ull*      masks   = (ull*)     (w + 20480 + (size_t)CAP * 8 + 16384 + 4096 + 16384); // 128 KB

  kz  <<<16, 256, 0, stream>>>(hist, sel, out, topScore);
  kA  <<<1024, 256, 0, stream>>>((const float4*)cls, n / 4, sel, hist, candKey, candIdx);
  kSel<<<64, 256, 0, stream>>>((const float4*)cls, n / 4, sel, hist, candKey, candIdx, srv);
  kF2 <<<SRVCAP / 64, 64, 0, stream>>>(box, ph, pw, sel, srv, out, topScore, obox);
  kG  <<<TOPK, 256, 0, stream>>>(obox, masks);
  kH  <<<1, 256, 0, stream>>>(topScore, masks, out);
}